// Round 1
// baseline (59.582 us; speedup 1.0000x reference)
//
#include <hip/hip_runtime.h>

#define NPTS   65536
#define RGRID  128
#define BLK    256
#define XBLK   64                       // blocks per plane
#define NPLANE 192                      // B*P = 64*3
#define PTS_PER_BLOCK (NPTS / XBLK)     // 1024
#define PTS_PER_THREAD (PTS_PER_BLOCK / BLK) // 4
#define NPARTIAL (XBLK * NPLANE)        // 12288

__global__ __launch_bounds__(BLK) void sd_kernel(
    const float* __restrict__ pred_params,   // (64,3,4)
    const float* __restrict__ pts,           // (N,3)
    const float* __restrict__ grid,          // (128,128,128,3)
    const float* __restrict__ gmin,          // (3,)
    const float* __restrict__ gmax,          // (3,)
    float* __restrict__ partials)            // (NPARTIAL,)
{
    const int pl = blockIdx.y;               // plane index 0..191 (uniform)
    const float nx = pred_params[pl * 4 + 0];
    const float ny = pred_params[pl * 4 + 1];
    const float nz = pred_params[pl * 4 + 2];
    const float dd = pred_params[pl * 4 + 3];

    const float g0x = gmin[0], g0y = gmin[1], g0z = gmin[2];
    const float sx = (float)(RGRID - 1) / (gmax[0] - g0x);
    const float sy = (float)(RGRID - 1) / (gmax[1] - g0y);
    const float sz = (float)(RGRID - 1) / (gmax[2] - g0z);

    const int base = blockIdx.x * PTS_PER_BLOCK + threadIdx.x;

    float acc = 0.0f;
#pragma unroll
    for (int k = 0; k < PTS_PER_THREAD; ++k) {
        const int n = base + k * BLK;
        const float px = pts[n * 3 + 0];
        const float py = pts[n * 3 + 1];
        const float pz = pts[n * 3 + 2];

        // proj = dot(p, nvec) + d
        const float proj = fmaf(px, nx, fmaf(py, ny, fmaf(pz, nz, dd)));
        const float t = -2.0f * proj;
        const float rx = fmaf(t, nx, px);
        const float ry = fmaf(t, ny, py);
        const float rz = fmaf(t, nz, pz);

        // grid index: clip(round((r - gmin) * (R-1)/(gmax-gmin)), 0, R-1)
        const float cx = (rx - g0x) * sx;
        const float cy = (ry - g0y) * sy;
        const float cz = (rz - g0z) * sz;
        const int i0 = (int)fminf(fmaxf(rintf(cx), 0.0f), (float)(RGRID - 1));
        const int i1 = (int)fminf(fmaxf(rintf(cy), 0.0f), (float)(RGRID - 1));
        const int i2 = (int)fminf(fmaxf(rintf(cz), 0.0f), (float)(RGRID - 1));

        const float* __restrict__ g = grid + (size_t)((i0 * RGRID + i1) * RGRID + i2) * 3;
        const float dx = rx - g[0];
        const float dy = ry - g[1];
        const float dz = rz - g[2];
        acc += sqrtf(fmaf(dx, dx, fmaf(dy, dy, dz * dz)));
    }

    // wave (64-lane) reduction, then cross-wave via LDS
    for (int off = 32; off > 0; off >>= 1)
        acc += __shfl_down(acc, off, 64);

    __shared__ float wsum[BLK / 64];
    if ((threadIdx.x & 63) == 0) wsum[threadIdx.x >> 6] = acc;
    __syncthreads();
    if (threadIdx.x == 0) {
        float s = 0.0f;
#pragma unroll
        for (int i = 0; i < BLK / 64; ++i) s += wsum[i];
        partials[blockIdx.y * XBLK + blockIdx.x] = s;
    }
}

__global__ __launch_bounds__(256) void finalize_kernel(
    const float* __restrict__ partials,
    const float* __restrict__ pred_params,   // (64,3,4)
    float* __restrict__ out)                 // (3,) : total, sd, r
{
    const int t = threadIdx.x;

    // ---- reduce sd partials (deterministic, double accumulation) ----
    __shared__ double sdl[256];
    double a = 0.0;
    for (int i = t; i < NPARTIAL; i += 256) a += (double)partials[i];
    sdl[t] = a;
    __syncthreads();
    for (int s = 128; s > 0; s >>= 1) {
        if (t < s) sdl[t] += sdl[t + s];
        __syncthreads();
    }

    // ---- regularizer: per-batch 3x3 normals gram - I ----
    __shared__ float rl[64];
    if (t < 64) {
        float nm[3][3];
#pragma unroll
        for (int p = 0; p < 3; ++p) {
            const float x = pred_params[(t * 3 + p) * 4 + 0];
            const float y = pred_params[(t * 3 + p) * 4 + 1];
            const float z = pred_params[(t * 3 + p) * 4 + 2];
            const float nrm = sqrtf(fmaf(x, x, fmaf(y, y, z * z)));
            const float inv = 1.0f / fmaxf(nrm, 1e-12f);
            nm[p][0] = x * inv; nm[p][1] = y * inv; nm[p][2] = z * inv;
        }
        float r = 0.0f;
#pragma unroll
        for (int p = 0; p < 3; ++p)
#pragma unroll
            for (int q = 0; q < 3; ++q) {
                float d = fmaf(nm[p][0], nm[q][0],
                          fmaf(nm[p][1], nm[q][1], nm[p][2] * nm[q][2]));
                if (p == q) d -= 1.0f;
                r = fmaf(d, d, r);
            }
        rl[t] = r;
    }
    __syncthreads();

    if (t == 0) {
        double rsum = 0.0;
        for (int i = 0; i < 64; ++i) rsum += (double)rl[i];
        const double sd = sdl[0] / (64.0 * (double)NPTS);
        const double rv = rsum / 64.0;
        out[0] = (float)(sd + 25.0 * rv);
        out[1] = (float)sd;
        out[2] = (float)rv;
    }
}

extern "C" void kernel_launch(void* const* d_in, const int* in_sizes, int n_in,
                              void* d_out, int out_size, void* d_ws, size_t ws_size,
                              hipStream_t stream) {
    const float* pred_params = (const float*)d_in[0];
    const float* pts         = (const float*)d_in[1];
    const float* grid        = (const float*)d_in[2];
    const float* gmin        = (const float*)d_in[3];
    const float* gmax        = (const float*)d_in[4];
    float* out = (float*)d_out;
    float* partials = (float*)d_ws;

    dim3 g1(XBLK, NPLANE, 1);
    sd_kernel<<<g1, BLK, 0, stream>>>(pred_params, pts, grid, gmin, gmax, partials);
    finalize_kernel<<<1, 256, 0, stream>>>(partials, pred_params, out);
}

// Round 2
// 48.342 us; speedup vs baseline: 1.2325x; 1.2325x over previous
//
#include <hip/hip_runtime.h>

#define NPTS   65536
#define RGRID  128
#define BLK    256
#define NPLANE 192                      // B*P = 64*3
#define PGRP   24                       // planes per block (group)
#define NGRP   (NPLANE / PGRP)          // 8
#define XBLK   (NPTS / BLK)             // 256 point-blocks
#define NPARTIAL (XBLK * NGRP)          // 2048

__global__ __launch_bounds__(BLK) void sd_kernel(
    const float* __restrict__ pred_params,   // (64,3,4)
    const float* __restrict__ pts,           // (N,3)
    const float* __restrict__ grid,          // (128,128,128,3)
    const float* __restrict__ gmin,          // (3,)
    const float* __restrict__ gmax,          // (3,)
    float* __restrict__ partials)            // (NPARTIAL,)
{
    __shared__ float sp[PGRP * 4];
    const int grp = blockIdx.y;              // plane group 0..7
    if (threadIdx.x < PGRP * 4)
        sp[threadIdx.x] = pred_params[grp * PGRP * 4 + threadIdx.x];

    const float g0x = gmin[0], g0y = gmin[1], g0z = gmin[2];
    const float sx = (float)(RGRID - 1) / (gmax[0] - g0x);
    const float sy = (float)(RGRID - 1) / (gmax[1] - g0y);
    const float sz = (float)(RGRID - 1) / (gmax[2] - g0z);
    __syncthreads();

    // one point per thread, loaded once
    const int n = blockIdx.x * BLK + threadIdx.x;
    const float px = pts[n * 3 + 0];
    const float py = pts[n * 3 + 1];
    const float pz = pts[n * 3 + 2];

    float acc = 0.0f;
#pragma unroll 4
    for (int p = 0; p < PGRP; ++p) {
        const float nx = sp[p * 4 + 0];      // uniform index -> LDS broadcast
        const float ny = sp[p * 4 + 1];
        const float nz = sp[p * 4 + 2];
        const float dd = sp[p * 4 + 3];

        const float proj = fmaf(px, nx, fmaf(py, ny, fmaf(pz, nz, dd)));
        const float t = -2.0f * proj;
        const float rx = fmaf(t, nx, px);
        const float ry = fmaf(t, ny, py);
        const float rz = fmaf(t, nz, pz);

        const float cx = (rx - g0x) * sx;
        const float cy = (ry - g0y) * sy;
        const float cz = (rz - g0z) * sz;
        const int i0 = (int)fminf(fmaxf(rintf(cx), 0.0f), (float)(RGRID - 1));
        const int i1 = (int)fminf(fmaxf(rintf(cy), 0.0f), (float)(RGRID - 1));
        const int i2 = (int)fminf(fmaxf(rintf(cz), 0.0f), (float)(RGRID - 1));

        const float* __restrict__ g = grid + (size_t)(((i0 * RGRID + i1) * RGRID + i2) * 3);
        const float dx = rx - g[0];
        const float dy = ry - g[1];
        const float dz = rz - g[2];
        acc += sqrtf(fmaf(dx, dx, fmaf(dy, dy, dz * dz)));
    }

    // wave (64-lane) reduction, then cross-wave via LDS
    for (int off = 32; off > 0; off >>= 1)
        acc += __shfl_down(acc, off, 64);

    __shared__ float wsum[BLK / 64];
    if ((threadIdx.x & 63) == 0) wsum[threadIdx.x >> 6] = acc;
    __syncthreads();
    if (threadIdx.x == 0) {
        float s = 0.0f;
#pragma unroll
        for (int i = 0; i < BLK / 64; ++i) s += wsum[i];
        partials[blockIdx.y * XBLK + blockIdx.x] = s;
    }
}

__global__ __launch_bounds__(256) void finalize_kernel(
    const float* __restrict__ partials,
    const float* __restrict__ pred_params,   // (64,3,4)
    float* __restrict__ out)                 // (3,) : total, sd, r
{
    const int t = threadIdx.x;

    // ---- reduce sd partials (deterministic, double accumulation) ----
    __shared__ double sdl[256];
    double a = 0.0;
    for (int i = t; i < NPARTIAL; i += 256) a += (double)partials[i];
    sdl[t] = a;
    __syncthreads();
    for (int s = 128; s > 0; s >>= 1) {
        if (t < s) sdl[t] += sdl[t + s];
        __syncthreads();
    }

    // ---- regularizer: per-batch 3x3 normals gram - I ----
    __shared__ float rl[64];
    if (t < 64) {
        float nm[3][3];
#pragma unroll
        for (int p = 0; p < 3; ++p) {
            const float x = pred_params[(t * 3 + p) * 4 + 0];
            const float y = pred_params[(t * 3 + p) * 4 + 1];
            const float z = pred_params[(t * 3 + p) * 4 + 2];
            const float nrm = sqrtf(fmaf(x, x, fmaf(y, y, z * z)));
            const float inv = 1.0f / fmaxf(nrm, 1e-12f);
            nm[p][0] = x * inv; nm[p][1] = y * inv; nm[p][2] = z * inv;
        }
        float r = 0.0f;
#pragma unroll
        for (int p = 0; p < 3; ++p)
#pragma unroll
            for (int q = 0; q < 3; ++q) {
                float d = fmaf(nm[p][0], nm[q][0],
                          fmaf(nm[p][1], nm[q][1], nm[p][2] * nm[q][2]));
                if (p == q) d -= 1.0f;
                r = fmaf(d, d, r);
            }
        rl[t] = r;
    }
    __syncthreads();

    if (t == 0) {
        double rsum = 0.0;
        for (int i = 0; i < 64; ++i) rsum += (double)rl[i];
        const double sd = sdl[0] / (64.0 * (double)NPTS);
        const double rv = rsum / 64.0;
        out[0] = (float)(sd + 25.0 * rv);
        out[1] = (float)sd;
        out[2] = (float)rv;
    }
}

extern "C" void kernel_launch(void* const* d_in, const int* in_sizes, int n_in,
                              void* d_out, int out_size, void* d_ws, size_t ws_size,
                              hipStream_t stream) {
    const float* pred_params = (const float*)d_in[0];
    const float* pts         = (const float*)d_in[1];
    const float* grid        = (const float*)d_in[2];
    const float* gmin        = (const float*)d_in[3];
    const float* gmax        = (const float*)d_in[4];
    float* out = (float*)d_out;
    float* partials = (float*)d_ws;

    dim3 g1(XBLK, NGRP, 1);
    sd_kernel<<<g1, BLK, 0, stream>>>(pred_params, pts, grid, gmin, gmax, partials);
    finalize_kernel<<<1, 256, 0, stream>>>(partials, pred_params, out);
}